// Round 7
// baseline (1919.136 us; speedup 1.0000x reference)
//
#include <hip/hip_runtime.h>
#include <hip/hip_bf16.h>

#define L_ROWS 8192
#define NUc 512
#define MH 4096      // L/2
#define KIN 1024     // 2*NU
#define NH 2048      // 4*NU
#define N_UNITS 25
#define CW 0.10897247358851332f
#define LN_EPS 1e-6f

typedef __bf16 bf16_t;
typedef __attribute__((ext_vector_type(8))) __bf16 bf16x8;
typedef __attribute__((ext_vector_type(4))) __bf16 bf16x4;
typedef __attribute__((ext_vector_type(4))) float f32x4;

#define GLD_LDS16(g, l) __builtin_amdgcn_global_load_lds( \
    (const __attribute__((address_space(1))) void*)(g),   \
    (__attribute__((address_space(3))) void*)(l), 16, 0, 0)

// Tiled fragment-native layout for gemm2 operands (H, w2t):
//   off(r,k; K) = ((r>>4)*(K>>3) + (k>>3))*128 + ((r&15)<<3) + (k&7)
// A wave's MFMA fragment (16 lanes x 8k, 4 quads) = 4 consecutive dense 256B
// blocks -> perfectly coalesced 16B/lane global loads, no LDS needed.

// ---------------------------------------------------------------- init
__global__ void init_misc(const float* __restrict__ x, bf16_t* __restrict__ xb,
                          const float* __restrict__ rs_f, const float* __restrict__ rs_r,
                          const float* __restrict__ rs_m,
                          float* __restrict__ sig, float* __restrict__ stats) {
    int i = blockIdx.x * 256 + threadIdx.x;           // 1,048,576 threads x 4 el
    {
        float4 v = *(const float4*)(x + (size_t)i * 4);
        bf16x4 p;
        p[0] = (__bf16)v.x; p[1] = (__bf16)v.y; p[2] = (__bf16)v.z; p[3] = (__bf16)v.w;
        *(bf16x4*)(xb + (size_t)i * 4) = p;
    }
    if (i < 3 * NUc) {
        const float* rs = (i < NUc) ? rs_f : (i < 2 * NUc ? rs_r : rs_m);
        float v = rs[i & (NUc - 1)];
        sig[i] = 1.0f / (1.0f + expf(-v));
    }
    if (i < N_UNITS * 2 * NH) stats[i] = 0.0f;
}

// ---------------------------------------------------------------- transposes
// w1t (row-major, for staged gemm1): out[C][R] = in[R][C]
__global__ void transpose_f32_bf16(const float* __restrict__ in, bf16_t* __restrict__ out,
                                   int R, int C) {
    __shared__ float t[32][33];
    int lx = threadIdx.x & 31, ly = threadIdx.x >> 5;   // 32 x 8
    int bx = blockIdx.x, by = blockIdx.y;
#pragma unroll
    for (int s = 0; s < 32; s += 8) {
        int r = by * 32 + ly + s, c = bx * 32 + lx;
        t[ly + s][lx] = in[(size_t)r * C + c];
    }
    __syncthreads();
#pragma unroll
    for (int s = 0; s < 32; s += 8) {
        int r = bx * 32 + ly + s, c = by * 32 + lx;
        out[(size_t)r * R + c] = (__bf16)t[lx][ly + s];
    }
}

// w2t in TILED layout: logical (r in [0,Rt)=KIN, k in [0,Kt)=NH), in = w2[Kt][Rt]
__global__ void transpose_f32_bf16_tiled(const float* __restrict__ in, bf16_t* __restrict__ out,
                                         int Rt, int Kt) {
    __shared__ float t[32][33];
    int lx = threadIdx.x & 31, ly = threadIdx.x >> 5;
    int bx = blockIdx.x, by = blockIdx.y;     // bx: r-dim/32, by: k-dim/32
#pragma unroll
    for (int s = 0; s < 32; s += 8) {
        int kk = by * 32 + ly + s, rr = bx * 32 + lx;
        t[ly + s][lx] = in[(size_t)kk * Rt + rr];
    }
    __syncthreads();
#pragma unroll
    for (int s = 0; s < 32; s += 8) {
        int r = bx * 32 + ly + s, k = by * 32 + lx;
        size_t off = ((size_t)(r >> 4) * (Kt >> 3) + (k >> 3)) * 128 + ((r & 15) << 3) + (k & 7);
        out[off] = (__bf16)t[lx][ly + s];
    }
}

// ---------------------------------------------------------------- GEMM1
// H = Ab @ W1 (staged-LDS, unchanged structure from R4; H written TILED)
__launch_bounds__(256, 4)
__global__ void gemm1_kernel(const bf16_t* __restrict__ Ab,
                             const bf16_t* __restrict__ Bt,
                             bf16_t* __restrict__ H,
                             float* __restrict__ colsum) {
    __shared__ __align__(16) bf16_t As[128 * 64];
    __shared__ __align__(16) bf16_t Bs[64 * 64];
    const int tid = threadIdx.x;
    const int wave = tid >> 6, lane = tid & 63;
    const int l16 = lane & 15, quad = lane >> 4;
    const int wm = wave >> 1, wn = wave & 1;
    const int bm0 = blockIdx.y * 128, bn0 = blockIdx.x * 64;

    f32x4 acc[4][2];
#pragma unroll
    for (int i = 0; i < 4; ++i)
#pragma unroll
        for (int j = 0; j < 2; ++j) acc[i][j] = (f32x4)(0.0f);

    const int rin = lane >> 3, usrc = (lane & 7) ^ (rin & 7);
    const bf16_t* pa = Ab + (size_t)(bm0 + wave * 8 + rin) * KIN + usrc * 8;
    const bf16_t* pb = Bt + (size_t)(bn0 + wave * 8 + rin) * KIN + usrc * 8;
    bf16_t* la = As + wave * 512 + lane * 8;
    bf16_t* lb = Bs + wave * 512 + lane * 8;
    const int sw = (l16 & 7) * 8;

    for (int k0 = 0; k0 < KIN; k0 += 64) {
#pragma unroll
        for (int s = 0; s < 4; ++s)
            GLD_LDS16(pa + (size_t)(s * 32) * KIN + k0, la + s * 2048);
#pragma unroll
        for (int s = 0; s < 2; ++s)
            GLD_LDS16(pb + (size_t)(s * 32) * KIN + k0, lb + s * 2048);
        __syncthreads();
        bf16x8 a[4][2], b[2][2];
#pragma unroll
        for (int h = 0; h < 2; ++h) {
            int u = ((h * 4 + quad) * 8) ^ sw;
#pragma unroll
            for (int i = 0; i < 4; ++i)
                a[i][h] = *(const bf16x8*)(As + (wm * 64 + i * 16 + l16) * 64 + u);
#pragma unroll
            for (int j = 0; j < 2; ++j)
                b[j][h] = *(const bf16x8*)(Bs + (wn * 32 + j * 16 + l16) * 64 + u);
        }
#pragma unroll
        for (int h = 0; h < 2; ++h)
#pragma unroll
            for (int i = 0; i < 4; ++i)
#pragma unroll
                for (int j = 0; j < 2; ++j)
                    acc[i][j] = __builtin_amdgcn_mfma_f32_16x16x32_bf16(b[j][h], a[i][h], acc[i][j], 0, 0, 0);
        __syncthreads();
    }

    // epilogue: write H in TILED layout (K = NH)
#pragma unroll
    for (int i = 0; i < 4; ++i) {
        int m = bm0 + wm * 64 + i * 16 + l16;
#pragma unroll
        for (int j = 0; j < 2; ++j) {
            int n = bn0 + wn * 32 + j * 16 + (quad << 2);
            bf16x4 p;
#pragma unroll
            for (int r = 0; r < 4; ++r) p[r] = (__bf16)acc[i][j][r];
            size_t off = ((size_t)(m >> 4) * (NH >> 3) + (n >> 3)) * 128 + ((m & 15) << 3) + (n & 7);
            *(bf16x4*)(H + off) = p;
        }
    }
#pragma unroll
    for (int j = 0; j < 2; ++j) {
#pragma unroll
        for (int r = 0; r < 4; ++r) {
            float s1 = 0.f, s2 = 0.f;
#pragma unroll
            for (int i = 0; i < 4; ++i) { float v = acc[i][j][r]; s1 += v; s2 += v * v; }
#pragma unroll
            for (int msk = 1; msk < 16; msk <<= 1) {
                s1 += __shfl_xor(s1, msk);
                s2 += __shfl_xor(s2, msk);
            }
            if (l16 == 0) {
                int n = bn0 + wn * 32 + j * 16 + (quad << 2) + r;
                atomicAdd(&colsum[n], s1);
                atomicAdd(&colsum[NH + n], s2);
            }
        }
    }
}

// ---------------------------------------------------------------- normalize
// elementwise on tiled H: flat idx f -> col = ((f>>7)&255)*8 + (f&7)
__global__ void norm_kernel(bf16_t* __restrict__ H, const float* __restrict__ stats) {
    int idx = blockIdx.x * 256 + threadIdx.x;          // 1,048,576 octets
    bf16x8 h = *(bf16x8*)(H + (size_t)idx * 8);
    int col8 = ((idx >> 4) & 255) * 8;                 // k-block base column
#pragma unroll
    for (int t = 0; t < 8; ++t) {
        float s1 = stats[col8 + t], s2 = stats[NH + col8 + t];
        float mean = s1 * (1.0f / MH);
        float var = s2 * (1.0f / MH) - mean * mean;
        float rstd = rsqrtf(var + LN_EPS);
        float v = ((float)h[t] - mean) * rstd;
        v = v > 0.f ? v : 0.2f * v;
        h[t] = (__bf16)v;
    }
    *(bf16x8*)(H + (size_t)idx * 8) = h;
}

// ---------------------------------------------------------------- GEMM2
// C[MH x KIN] = Hn @ W2, BOTH operands tiled + barrier-free K-loop.
// 4 waves m-stacked: wave = 32m x 64n. 2-stage ping-pong prefetch, no LDS,
// no __syncthreads -> compiler emits fine-grained vmcnt, never a full drain.
__launch_bounds__(256, 4)
__global__ void gemm2_kernel(const bf16_t* __restrict__ Hn,
                             const bf16_t* __restrict__ Bt,   // tiled w2t
                             const float* __restrict__ yin,
                             float* __restrict__ yout,
                             bf16_t* __restrict__ ybout,
                             const float* __restrict__ sig,
                             const float* __restrict__ b2,
                             int mode) {
    const int tid = threadIdx.x;
    const int wave = tid >> 6, lane = tid & 63;
    const int l16 = lane & 15, quad = lane >> 4;
    const int bm0 = blockIdx.y * 128, bn0 = blockIdx.x * 64;

    f32x4 acc[2][4];
#pragma unroll
    for (int i = 0; i < 2; ++i)
#pragma unroll
        for (int j = 0; j < 4; ++j) acc[i][j] = (f32x4)(0.0f);

    // fragment base pointers (tiled, K=NH: 256 k-blocks per row-block)
    const int arb = (bm0 >> 4) + wave * 2;            // A row-blocks arb, arb+1
    const int brb = (bn0 >> 4);                        // B row-blocks brb..brb+3
    const bf16_t* pa = Hn + ((size_t)arb * 256 + quad) * 128 + l16 * 8;
    const bf16_t* pb = Bt + ((size_t)brb * 256 + quad) * 128 + l16 * 8;

    bf16x8 aP[2][2], bP[2][4];
#pragma unroll
    for (int i = 0; i < 2; ++i)
        aP[0][i] = *(const bf16x8*)(pa + (size_t)i * 256 * 128);
#pragma unroll
    for (int j = 0; j < 4; ++j)
        bP[0][j] = *(const bf16x8*)(pb + (size_t)j * 256 * 128);

    int p = 0;
    for (int kb = 0; kb < 256; kb += 4, p ^= 1) {
        if (kb + 4 < 256) {
#pragma unroll
            for (int i = 0; i < 2; ++i)
                aP[p ^ 1][i] = *(const bf16x8*)(pa + ((size_t)i * 256 + kb + 4) * 128);
#pragma unroll
            for (int j = 0; j < 4; ++j)
                bP[p ^ 1][j] = *(const bf16x8*)(pb + ((size_t)j * 256 + kb + 4) * 128);
        }
#pragma unroll
        for (int i = 0; i < 2; ++i)
#pragma unroll
            for (int j = 0; j < 4; ++j)
                acc[i][j] = __builtin_amdgcn_mfma_f32_16x16x32_bf16(bP[p][j], aP[p][i], acc[i][j], 0, 0, 0);
    }

    // epilogue: bias, residual, permutation scatter (fp32 + bf16 copies)
#pragma unroll
    for (int i = 0; i < 2; ++i) {
        int m = bm0 + wave * 32 + i * 16 + l16;
#pragma unroll
        for (int j = 0; j < 4; ++j) {
            int n0 = bn0 + j * 16 + (quad << 2);
            int yrow = 2 * m + (n0 >> 9);
            int ycol = n0 & (NUc - 1);
            float sgv[4]; *(float4*)sgv = *(const float4*)(sig + ycol);
            float yv[4];  *(float4*)yv  = *(const float4*)(yin + (size_t)yrow * NUc + ycol);
            float bb[4];  *(float4*)bb  = *(const float4*)(b2 + n0);
            int dest = (mode == 0) ? ((yrow < MH) ? 2 * yrow : 2 * yrow - (L_ROWS - 1))
                     : (mode == 1) ? (((yrow & 1) ? MH + (yrow >> 1) : (yrow >> 1)))
                     : yrow;
            float o[4];
            bf16x4 q;
#pragma unroll
            for (int r = 0; r < 4; ++r) {
                o[r] = sgv[r] * yv[r] + (acc[i][j][r] + bb[r]) * CW;
                q[r] = (__bf16)o[r];
            }
            *(float4*)(yout + (size_t)dest * NUc + ycol) = *(float4*)o;
            *(bf16x4*)(ybout + (size_t)dest * NUc + ycol) = q;
        }
    }
}

// ---------------------------------------------------------------- launch
extern "C" void kernel_launch(void* const* d_in, const int* in_sizes, int n_in,
                              void* d_out, int out_size, void* d_ws, size_t ws_size,
                              hipStream_t stream) {
    (void)in_sizes; (void)n_in; (void)out_size; (void)ws_size;
    const float* x    = (const float*)d_in[0];
    const float* rs_f = (const float*)d_in[1];
    const float* w1[3] = {(const float*)d_in[2], (const float*)d_in[6], (const float*)d_in[10]};
    const float* w2[3] = {(const float*)d_in[3], (const float*)d_in[7], (const float*)d_in[11]};
    const float* b2[3] = {(const float*)d_in[4], (const float*)d_in[8], (const float*)d_in[12]};
    const float* rs_r = (const float*)d_in[5];
    const float* rs_m = (const float*)d_in[9];

    float*  y0    = (float*)d_ws;                          // 4M fp32
    float*  y1    = y0 + (size_t)MH * KIN;                 // 4M fp32
    bf16_t* yb    = (bf16_t*)(y1 + (size_t)MH * KIN);      // 4M bf16 (row-major)
    bf16_t* H     = yb + (size_t)MH * KIN;                 // 8M bf16 (TILED)
    bf16_t* w1t   = H + (size_t)MH * NH;                   // 3 x 2M bf16 (row-major)
    bf16_t* w2t   = w1t + 3 * (size_t)NH * KIN;            // 3 x 2M bf16 (TILED)
    float*  sig   = (float*)(w2t + 3 * (size_t)KIN * NH);  // 1536 fp32
    float*  stats = sig + 3 * NUc;                         // 25 x 2 x 2048 fp32

    init_misc<<<4096, 256, 0, stream>>>(x, yb, rs_f, rs_r, rs_m, sig, stats);
    for (int t = 0; t < 3; ++t) {
        transpose_f32_bf16<<<dim3(NH / 32, KIN / 32), 256, 0, stream>>>(w1[t], w1t + (size_t)t * NH * KIN, KIN, NH);
        transpose_f32_bf16_tiled<<<dim3(KIN / 32, NH / 32), 256, 0, stream>>>(w2[t], w2t + (size_t)t * KIN * NH, KIN, NH);
    }

    const float* cur = x;
    float* bufs[2] = {y0, y1};
    for (int u = 0; u < N_UNITS; ++u) {
        int tag  = (u < 12) ? 0 : (u < 24 ? 1 : 2);
        int mode = (u < 12) ? 0 : (u < 24 ? 1 : 2);
        float* st = stats + (size_t)u * 2 * NH;
        float* out = (u == N_UNITS - 1) ? (float*)d_out : bufs[u & 1];
        gemm1_kernel<<<dim3(NH / 64, MH / 128), 256, 0, stream>>>(
            yb, w1t + (size_t)tag * NH * KIN, H, st);
        norm_kernel<<<4096, 256, 0, stream>>>(H, st);
        gemm2_kernel<<<dim3(KIN / 64, MH / 128), 256, 0, stream>>>(
            H, w2t + (size_t)tag * KIN * NH, cur, out, yb,
            sig + tag * NUc, b2[tag], mode);
        cur = out;
    }
}

// Round 8
// 1848.974 us; speedup vs baseline: 1.0379x; 1.0379x over previous
//
#include <hip/hip_runtime.h>
#include <hip/hip_bf16.h>

#define L_ROWS 8192
#define NUc 512
#define MH 4096      // L/2
#define KIN 1024     // 2*NU
#define NH 2048      // 4*NU
#define N_UNITS 25
#define CW 0.10897247358851332f
#define LN_EPS 1e-6f

typedef __bf16 bf16_t;
typedef __attribute__((ext_vector_type(8))) __bf16 bf16x8;
typedef __attribute__((ext_vector_type(4))) __bf16 bf16x4;
typedef __attribute__((ext_vector_type(4))) float f32x4;

#define GLD_LDS16(g, l) __builtin_amdgcn_global_load_lds( \
    (const __attribute__((address_space(1))) void*)(g),   \
    (__attribute__((address_space(3))) void*)(l), 16, 0, 0)

// y is stored FLAT/natural [8192][512]; the Benes shuffles (ROR/ROL = index
// bit-rotations) are folded into the READ side: logical pair-row m, half h of
// unit u maps to stored flat row
//   mode_r 0 (unit 0):        R = 2m + h
//   mode_r 1 (units 1..12):   R = m + 4096h          (prev trailing ROR)
//   mode_r 2 (units 13..24):  R = 4m+2h (m<2048) else 4m+2h+1-8192  (ROL)
// Note pair(pr,n) <-> flat linear offset pr*1024 + n (identity reshape).

// ---------------------------------------------------------------- init
__global__ void init_misc(const float* __restrict__ x, bf16_t* __restrict__ xb,
                          const float* __restrict__ rs_f, const float* __restrict__ rs_r,
                          const float* __restrict__ rs_m,
                          float* __restrict__ sig, float* __restrict__ stats) {
    int i = blockIdx.x * 256 + threadIdx.x;           // 1,048,576 threads x 4 el
    {
        float4 v = *(const float4*)(x + (size_t)i * 4);
        bf16x4 p;
        p[0] = (__bf16)v.x; p[1] = (__bf16)v.y; p[2] = (__bf16)v.z; p[3] = (__bf16)v.w;
        *(bf16x4*)(xb + (size_t)i * 4) = p;
    }
    if (i < 3 * NUc) {
        const float* rs = (i < NUc) ? rs_f : (i < 2 * NUc ? rs_r : rs_m);
        float v = rs[i & (NUc - 1)];
        sig[i] = 1.0f / (1.0f + expf(-v));
    }
    if (i < N_UNITS * 2 * NH) stats[i] = 0.0f;
}

// ---------------------------------------------------------------- transpose
__global__ void transpose_f32_bf16(const float* __restrict__ in, bf16_t* __restrict__ out,
                                   int R, int C) {
    __shared__ float t[32][33];
    int lx = threadIdx.x & 31, ly = threadIdx.x >> 5;   // 32 x 8
    int bx = blockIdx.x, by = blockIdx.y;
#pragma unroll
    for (int s = 0; s < 32; s += 8) {
        int r = by * 32 + ly + s, c = bx * 32 + lx;
        t[ly + s][lx] = in[(size_t)r * C + c];
    }
    __syncthreads();
#pragma unroll
    for (int s = 0; s < 32; s += 8) {
        int r = bx * 32 + ly + s, c = by * 32 + lx;
        out[(size_t)r * R + c] = (__bf16)t[lx][ly + s];
    }
}

// ---------------------------------------------------------------- GEMM1
// H[MH x NH] = A_logical[MH x KIN](bf16, row-gathered from flat Y) @ W1
// tile 128(M) x 64(N), BK=64, 2x2 wave split
__launch_bounds__(256, 4)
__global__ void gemm1_kernel(const bf16_t* __restrict__ Y,
                             const bf16_t* __restrict__ Bt,
                             bf16_t* __restrict__ H,
                             float* __restrict__ colsum, int mode_r) {
    __shared__ __align__(16) bf16_t As[128 * 64];
    __shared__ __align__(16) bf16_t Bs[64 * 64];
    const int tid = threadIdx.x;
    const int wave = tid >> 6, lane = tid & 63;
    const int l16 = lane & 15, quad = lane >> 4;
    const int wm = wave >> 1, wn = wave & 1;
    const int bm0 = blockIdx.y * 128, bn0 = blockIdx.x * 64;

    f32x4 acc[4][2];
#pragma unroll
    for (int i = 0; i < 4; ++i)
#pragma unroll
        for (int j = 0; j < 2; ++j) acc[i][j] = (f32x4)(0.0f);

    const int rin = lane >> 3, usrc = (lane & 7) ^ (rin & 7);
    // source flat rows for this lane's logical pair-rows, per segment s, half h
    int Rh[2][4];
#pragma unroll
    for (int s = 0; s < 4; ++s) {
        int m = bm0 + wave * 8 + rin + s * 32;
#pragma unroll
        for (int h = 0; h < 2; ++h)
            Rh[h][s] = (mode_r == 0) ? (2 * m + h)
                     : (mode_r == 1) ? (m + (h << 12))
                     : ((m < 2048) ? (4 * m + 2 * h) : (4 * m + 2 * h + 1 - 8192));
    }
    const bf16_t* pb = Bt + (size_t)(bn0 + wave * 8 + rin) * KIN + usrc * 8;
    bf16_t* la = As + wave * 512 + lane * 8;
    bf16_t* lb = Bs + wave * 512 + lane * 8;
    const int sw = (l16 & 7) * 8;

    for (int k0 = 0; k0 < KIN; k0 += 64) {
        const int h = k0 >> 9;
        const int kc = (k0 & 511) + usrc * 8;
#pragma unroll
        for (int s = 0; s < 4; ++s)
            GLD_LDS16(Y + (size_t)Rh[h][s] * 512 + kc, la + s * 2048);
#pragma unroll
        for (int s = 0; s < 2; ++s)
            GLD_LDS16(pb + (size_t)(s * 32) * KIN + k0, lb + s * 2048);
        __syncthreads();
        bf16x8 a[4][2], b[2][2];
#pragma unroll
        for (int hh = 0; hh < 2; ++hh) {
            int u = ((hh * 4 + quad) * 8) ^ sw;
#pragma unroll
            for (int i = 0; i < 4; ++i)
                a[i][hh] = *(const bf16x8*)(As + (wm * 64 + i * 16 + l16) * 64 + u);
#pragma unroll
            for (int j = 0; j < 2; ++j)
                b[j][hh] = *(const bf16x8*)(Bs + (wn * 32 + j * 16 + l16) * 64 + u);
        }
#pragma unroll
        for (int hh = 0; hh < 2; ++hh)
#pragma unroll
            for (int i = 0; i < 4; ++i)
#pragma unroll
                for (int j = 0; j < 2; ++j)
                    acc[i][j] = __builtin_amdgcn_mfma_f32_16x16x32_bf16(b[j][hh], a[i][hh], acc[i][j], 0, 0, 0);
        __syncthreads();
    }

    // epilogue: H row-major; lane holds row m, 4 consecutive cols
#pragma unroll
    for (int i = 0; i < 4; ++i) {
        int m = bm0 + wm * 64 + i * 16 + l16;
#pragma unroll
        for (int j = 0; j < 2; ++j) {
            int n = bn0 + wn * 32 + j * 16 + (quad << 2);
            bf16x4 p;
#pragma unroll
            for (int r = 0; r < 4; ++r) p[r] = (__bf16)acc[i][j][r];
            *(bf16x4*)(H + (size_t)m * NH + n) = p;
        }
    }
#pragma unroll
    for (int j = 0; j < 2; ++j) {
#pragma unroll
        for (int r = 0; r < 4; ++r) {
            float s1 = 0.f, s2 = 0.f;
#pragma unroll
            for (int i = 0; i < 4; ++i) { float v = acc[i][j][r]; s1 += v; s2 += v * v; }
#pragma unroll
            for (int msk = 1; msk < 16; msk <<= 1) {
                s1 += __shfl_xor(s1, msk);
                s2 += __shfl_xor(s2, msk);
            }
            if (l16 == 0) {
                int n = bn0 + wn * 32 + j * 16 + (quad << 2) + r;
                atomicAdd(&colsum[n], s1);
                atomicAdd(&colsum[NH + n], s2);
            }
        }
    }
}

// ---------------------------------------------------------------- normalize
__global__ void norm_kernel(bf16_t* __restrict__ H, const float* __restrict__ stats) {
    int idx = blockIdx.x * 256 + threadIdx.x;          // 1,048,576 octets
    bf16x8 h = *(bf16x8*)(H + (size_t)idx * 8);
    int col = (idx * 8) & (NH - 1);
#pragma unroll
    for (int t = 0; t < 8; ++t) {
        float s1 = stats[col + t], s2 = stats[NH + col + t];
        float mean = s1 * (1.0f / MH);
        float var = s2 * (1.0f / MH) - mean * mean;
        float rstd = rsqrtf(var + LN_EPS);
        float v = ((float)h[t] - mean) * rstd;
        v = v > 0.f ? v : 0.2f * v;
        h[t] = (__bf16)v;
    }
    *(bf16x8*)(H + (size_t)idx * 8) = h;
}

// ---------------------------------------------------------------- GEMM2
// C[MH x KIN] = Hn @ W2 (staged LDS, BK=128, R5 K-loop). Epilogue: C through
// padded LDS transpose -> fully coalesced flat writes (natural order);
// residual gathered from flat yin via mode_r row formula.
__launch_bounds__(256, 2)
__global__ void gemm2_kernel(const bf16_t* __restrict__ Hn,
                             const bf16_t* __restrict__ Bt,
                             const float* __restrict__ yin,
                             float* __restrict__ yout,
                             bf16_t* __restrict__ ybout,
                             const float* __restrict__ sig,
                             const float* __restrict__ b2,
                             int mode_r) {
    __shared__ __align__(16) bf16_t smem[128 * 128 + 64 * 128];   // 48 KB
    bf16_t* As = smem;
    bf16_t* Bs = smem + 128 * 128;
    const int tid = threadIdx.x;
    const int wave = tid >> 6, lane = tid & 63;
    const int l16 = lane & 15, quad = lane >> 4;
    const int wm = wave >> 1, wn = wave & 1;
    const int bm0 = blockIdx.y * 128, bn0 = blockIdx.x * 64;

    f32x4 acc[4][2];
#pragma unroll
    for (int i = 0; i < 4; ++i)
#pragma unroll
        for (int j = 0; j < 2; ++j) acc[i][j] = (f32x4)(0.0f);

    const int r4 = lane >> 4;
    const int pu = lane & 15;
    bf16_t* la = As + lane * 8;
    bf16_t* lb = Bs + lane * 8;
    const int swl = (l16 & 7);

    for (int k0 = 0; k0 < NH; k0 += 128) {
#pragma unroll
        for (int t = 0; t < 8; ++t) {
            int row = wave * 32 + t * 4 + r4;
            int u = (pu & 8) | ((pu & 7) ^ (row & 7));
            GLD_LDS16(Hn + (size_t)(bm0 + row) * NH + k0 + u * 8,
                      la + (wave * 32 + t * 4) * 128);
        }
#pragma unroll
        for (int t = 0; t < 4; ++t) {
            int row = wave * 16 + t * 4 + r4;
            int u = (pu & 8) | ((pu & 7) ^ (row & 7));
            GLD_LDS16(Bt + (size_t)(bn0 + row) * NH + k0 + u * 8,
                      lb + (wave * 16 + t * 4) * 128);
        }
        __syncthreads();
#pragma unroll
        for (int h = 0; h < 4; ++h) {
            int ub = h * 4 + quad;
            int uoff = ((ub & 8) | ((ub & 7) ^ swl)) * 8;
            bf16x8 a[4], b[2];
#pragma unroll
            for (int i = 0; i < 4; ++i)
                a[i] = *(const bf16x8*)(As + (wm * 64 + i * 16 + l16) * 128 + uoff);
#pragma unroll
            for (int j = 0; j < 2; ++j)
                b[j] = *(const bf16x8*)(Bs + (wn * 32 + j * 16 + l16) * 128 + uoff);
#pragma unroll
            for (int i = 0; i < 4; ++i)
#pragma unroll
                for (int j = 0; j < 2; ++j)
                    acc[i][j] = __builtin_amdgcn_mfma_f32_16x16x32_bf16(b[j], a[i], acc[i][j], 0, 0, 0);
        }
        __syncthreads();
    }

    // ---- epilogue: stage C (128x64 fp32, padded stride 68) in LDS ----
    float* Cs = (float*)smem;                     // 128*68*4 = 34.8 KB < 48 KB
#pragma unroll
    for (int i = 0; i < 4; ++i) {
        int ml = wm * 64 + i * 16 + l16;
#pragma unroll
        for (int j = 0; j < 2; ++j) {
            int nl = wn * 32 + j * 16 + (quad << 2);
            *(f32x4*)(Cs + ml * 68 + nl) = acc[i][j];
        }
    }
    __syncthreads();
    const int hh = bn0 >> 9;
#pragma unroll
    for (int st = 0; st < 8; ++st) {
        int rr = st * 16 + (tid >> 4);            // local pair-row
        int cc = (tid & 15) * 4;                  // local col
        f32x4 cv = *(const f32x4*)(Cs + rr * 68 + cc);
        int pr = bm0 + rr;
        int n = bn0 + cc;
        int nc = n & 511;
        int Rs = (mode_r == 0) ? (2 * pr + hh)
               : (mode_r == 1) ? (pr + (hh << 12))
               : ((pr < 2048) ? (4 * pr + 2 * hh) : (4 * pr + 2 * hh + 1 - 8192));
        float sg[4]; *(float4*)sg = *(const float4*)(sig + nc);
        float yv[4]; *(float4*)yv = *(const float4*)(yin + (size_t)Rs * 512 + nc);
        float bb[4]; *(float4*)bb = *(const float4*)(b2 + n);
        float o[4];
        bf16x4 q;
#pragma unroll
        for (int r = 0; r < 4; ++r) {
            o[r] = sg[r] * yv[r] + (cv[r] + bb[r]) * CW;
            q[r] = (__bf16)o[r];
        }
        *(float4*)(yout + (size_t)pr * 1024 + n) = *(float4*)o;
        *(bf16x4*)(ybout + (size_t)pr * 1024 + n) = q;
    }
}

// ---------------------------------------------------------------- launch
extern "C" void kernel_launch(void* const* d_in, const int* in_sizes, int n_in,
                              void* d_out, int out_size, void* d_ws, size_t ws_size,
                              hipStream_t stream) {
    (void)in_sizes; (void)n_in; (void)out_size; (void)ws_size;
    const float* x    = (const float*)d_in[0];
    const float* rs_f = (const float*)d_in[1];
    const float* w1[3] = {(const float*)d_in[2], (const float*)d_in[6], (const float*)d_in[10]};
    const float* w2[3] = {(const float*)d_in[3], (const float*)d_in[7], (const float*)d_in[11]};
    const float* b2[3] = {(const float*)d_in[4], (const float*)d_in[8], (const float*)d_in[12]};
    const float* rs_r = (const float*)d_in[5];
    const float* rs_m = (const float*)d_in[9];

    float*  y0    = (float*)d_ws;                          // 4M fp32 (flat y)
    float*  y1    = y0 + (size_t)MH * KIN;                 // 4M fp32
    bf16_t* yb    = (bf16_t*)(y1 + (size_t)MH * KIN);      // 4M bf16 (flat y)
    bf16_t* H     = yb + (size_t)MH * KIN;                 // 8M bf16 (row-major)
    bf16_t* w1t   = H + (size_t)MH * NH;                   // 3 x 2M bf16
    bf16_t* w2t   = w1t + 3 * (size_t)NH * KIN;            // 3 x 2M bf16
    float*  sig   = (float*)(w2t + 3 * (size_t)KIN * NH);  // 1536 fp32
    float*  stats = sig + 3 * NUc;                         // 25 x 2 x 2048 fp32

    init_misc<<<4096, 256, 0, stream>>>(x, yb, rs_f, rs_r, rs_m, sig, stats);
    for (int t = 0; t < 3; ++t) {
        transpose_f32_bf16<<<dim3(NH / 32, KIN / 32), 256, 0, stream>>>(w1[t], w1t + (size_t)t * NH * KIN, KIN, NH);
        transpose_f32_bf16<<<dim3(KIN / 32, NH / 32), 256, 0, stream>>>(w2[t], w2t + (size_t)t * KIN * NH, NH, KIN);
    }

    const float* cur = x;
    float* bufs[2] = {y0, y1};
    for (int u = 0; u < N_UNITS; ++u) {
        int tag    = (u < 12) ? 0 : (u < 24 ? 1 : 2);
        int mode_r = (u == 0) ? 0 : (u <= 12 ? 1 : 2);
        float* st = stats + (size_t)u * 2 * NH;
        float* out = (u == N_UNITS - 1) ? (float*)d_out : bufs[u & 1];
        gemm1_kernel<<<dim3(NH / 64, MH / 128), 256, 0, stream>>>(
            yb, w1t + (size_t)tag * NH * KIN, H, st, mode_r);
        norm_kernel<<<4096, 256, 0, stream>>>(H, st);
        gemm2_kernel<<<dim3(KIN / 64, MH / 128), 256, 0, stream>>>(
            H, w2t + (size_t)tag * KIN * NH, cur, out, yb,
            sig + tag * NUc, b2[tag], mode_r);
        cur = out;
    }
}